// Round 1
// 6046.198 us; speedup vs baseline: 2.9852x; 2.9852x over previous
//
#include <hip/hip_runtime.h>
#include <cstdint>

#define BATCH 64
#define SEQ   512
#define DIN   862
#define DPAD  896
#define HID   1024
#define NG    4096

typedef _Float16 f16;
typedef __attribute__((ext_vector_type(8))) _Float16 f16x8;
typedef __attribute__((ext_vector_type(4))) float    f32x4;

// ---------------- async global->LDS (16B per lane, wave-uniform LDS base) -------------
__device__ __forceinline__ void glds16(const f16* g, f16* l) {
    auto gp = (const __attribute__((address_space(1))) void*)(uintptr_t)g;
    auto lp = (__attribute__((address_space(3))) void*)(uint32_t)(uintptr_t)l;
    __builtin_amdgcn_global_load_lds(gp, lp, 16, 0, 0);
}

__device__ __forceinline__ float sigf(float x) {
    return __builtin_amdgcn_rcpf(1.f + __expf(-x));
}
__device__ __forceinline__ float tanh_fast(float x) {
    float xx = fminf(15.f, fmaxf(-15.f, x));
    float e = __expf(2.f * xx);
    return (e - 1.f) * __builtin_amdgcn_rcpf(e + 1.f);
}

// XG layout: [t][bs(4)][jg(64)][g(4)][bl(16)][jl(16)]  (f16, bias included)
__device__ __forceinline__ long xg_index(int t, int b, int n) {
    int bs = b >> 4, bl = b & 15;
    int g = n >> 10, jh = n & 1023;
    int jg = jh >> 4, jl = jh & 15;
    return (((((long)t * 4 + bs) * 64 + jg) * 4 + g) * 16 + bl) * 16 + jl;
}

// ---------------- prep: fp32->fp16 conversions, padding, bias sums, barrier zero ------
__global__ __launch_bounds__(256) void prep_kernel(
    const float* __restrict__ x,
    const float* __restrict__ Wih0, const float* __restrict__ Whh0,
    const float* __restrict__ bih0, const float* __restrict__ bhh0,
    const float* __restrict__ Wih1, const float* __restrict__ Whh1,
    const float* __restrict__ bih1, const float* __restrict__ bhh1,
    f16* __restrict__ xh, f16* __restrict__ W0h, f16* __restrict__ Wh0h,
    f16* __restrict__ W1h, f16* __restrict__ Wh1h,
    float* __restrict__ b0, float* __restrict__ b1, unsigned* __restrict__ bar)
{
    long tid = (long)blockIdx.x * blockDim.x + threadIdx.x;
    long np  = (long)gridDim.x * blockDim.x;
    for (long i = tid; i < (long)BATCH * SEQ * DPAD; i += np) {
        long m = i / DPAD, k = i % DPAD;
        xh[i] = (k < DIN) ? (f16)x[m * DIN + k] : (f16)0.f;
    }
    for (long i = tid; i < (long)NG * DPAD; i += np) {
        long n = i / DPAD, k = i % DPAD;
        W0h[i] = (k < DIN) ? (f16)Wih0[n * DIN + k] : (f16)0.f;
    }
    for (long i = tid; i < (long)NG * HID; i += np) {
        Wh0h[i] = (f16)Whh0[i];
        W1h[i]  = (f16)Wih1[i];
        Wh1h[i] = (f16)Whh1[i];
    }
    for (long i = tid; i < NG; i += np) { b0[i] = bih0[i] + bhh0[i]; b1[i] = bih1[i] + bhh1[i]; }
    for (long i = tid; i < 2048; i += np) bar[i] = 0u;
}

// ---------------- f16 GEMM: gates[m][n] = A[m][:K] . Bw[n][:K] + bias[n] --------------
// A [32768][K], Bw [4096][K] (row-major, = W^T applied), out = XG layout (f16).
// mode 1: A rows are m = b*512 + t   (layer-1 input x)
// mode 2: A rows are m = t*64 + b    (layer-2 input h1)
__global__ __launch_bounds__(256) void gemm_f16(
    const f16* __restrict__ A, const f16* __restrict__ Bw,
    const float* __restrict__ bias, f16* __restrict__ out, int K, int mode)
{
    __shared__ f16 smem[2 * 128 * 32];   // A tile | B tile, 8KB each
    const int tid  = threadIdx.x;
    const int lane = tid & 63, wave = tid >> 6;
    const int wm = wave >> 1, wn = wave & 1;
    const int quad = lane >> 4, l15 = lane & 15;
    const int bm = blockIdx.x >> 5, bn = blockIdx.x & 31;
    const long m0 = (long)bm * 128, n0 = (long)bn * 128;
    const int r4 = lane >> 2, g4 = lane & 3;

    f32x4 acc[4][4];
#pragma unroll
    for (int i = 0; i < 4; ++i)
#pragma unroll
        for (int j = 0; j < 4; ++j)
#pragma unroll
            for (int r = 0; r < 4; ++r) acc[i][j][r] = 0.f;

#pragma unroll 1
    for (int kk = 0; kk < K; kk += 32) {
#pragma unroll
        for (int c = 0; c < 2; ++c) {
            int idx = wave * 2 + c;
            int lr  = idx * 16 + r4;
            int gs  = g4 ^ ((lr >> 1) & 3);          // XOR-swizzled source granule
            glds16(A  + (m0 + lr) * (long)K + kk + gs * 8, smem + idx * 512);
            glds16(Bw + (n0 + lr) * (long)K + kk + gs * 8, smem + 4096 + idx * 512);
        }
        __syncthreads();
        f16x8 af[4], bf[4];
#pragma unroll
        for (int i = 0; i < 4; ++i) {
            int lr = 64 * wm + 16 * i + l15;
            int sl = quad ^ ((lr >> 1) & 3);
            af[i] = *(const f16x8*)(smem + lr * 32 + sl * 8);
        }
#pragma unroll
        for (int j = 0; j < 4; ++j) {
            int lr = 64 * wn + 16 * j + l15;
            int sl = quad ^ ((lr >> 1) & 3);
            bf[j] = *(const f16x8*)(smem + 4096 + lr * 32 + sl * 8);
        }
#pragma unroll
        for (int i = 0; i < 4; ++i)
#pragma unroll
            for (int j = 0; j < 4; ++j)
                acc[i][j] = __builtin_amdgcn_mfma_f32_16x16x32_f16(af[i], bf[j], acc[i][j], 0, 0, 0);
        __syncthreads();
    }

#pragma unroll
    for (int j = 0; j < 4; ++j) {
        int n = (int)n0 + 64 * wn + 16 * j + l15;
        float bv = bias[n];
#pragma unroll
        for (int i = 0; i < 4; ++i) {
#pragma unroll
            for (int r = 0; r < 4; ++r) {
                int m = (int)m0 + 64 * wm + 16 * i + quad * 4 + r;
                int t, b;
                if (mode == 1) { b = m >> 9; t = m & 511; }
                else           { t = m >> 6; b = m & 63; }
                out[xg_index(t, b, n)] = (f16)(acc[i][j][r] + bv);
            }
        }
    }
}

// ---------------- fence-free grid barrier ---------------------------------------------
// All cross-block data (h) is exchanged via sc1 (agent-scope, write-through) atomics,
// so NO buffer_wbl2 / buffer_inv is needed here. s_waitcnt vmcnt(0) by every thread
// drains its write-through stores to the coherence point before its block signals.
__device__ __forceinline__ void grid_barrier_nf(unsigned* bar, unsigned target) {
    asm volatile("s_waitcnt vmcnt(0)" ::: "memory");
    __syncthreads();
    if (threadIdx.x == 0) {
        unsigned grp = blockIdx.x >> 4;
        unsigned prev = __hip_atomic_fetch_add(&bar[grp * 32], 1u, __ATOMIC_RELAXED, __HIP_MEMORY_SCOPE_AGENT);
        if ((prev & 15u) == 15u) {
            unsigned pr = __hip_atomic_fetch_add(&bar[512], 1u, __ATOMIC_RELAXED, __HIP_MEMORY_SCOPE_AGENT);
            if ((pr & 15u) == 15u)
                __hip_atomic_store(&bar[544], target, __ATOMIC_RELAXED, __HIP_MEMORY_SCOPE_AGENT);
        }
        while (__hip_atomic_load(&bar[544], __ATOMIC_RELAXED, __HIP_MEMORY_SCOPE_AGENT) < target)
            __builtin_amdgcn_s_sleep(1);
    }
    __syncthreads();
}

// ---------------- persistent LSTM layer -----------------------------------------------
// 256 blocks = 4 batch-slices (bs) x 64 hidden-groups (jg, 16 hidden units each).
// h is published with agent-scope write-through atomic stores (packed f16 pairs) and
// consumed with agent-scope atomic loads (bypass the non-coherent per-XCD L2), so the
// per-step grid barrier needs no L2 writeback/invalidate. W_hh fragments are pinned in
// VGPRs with an empty asm so the compiler cannot rematerialize the loads per step.
__global__ __launch_bounds__(256, 1) void lstm_layer(
    const f16* __restrict__ xg, const f16* __restrict__ Whh,
    f16* __restrict__ hseq, float* __restrict__ out32, unsigned* __restrict__ bar)
{
    __shared__ float P[4 * 4 * 16 * 17];   // [src w][g][b 16][j 16+pad] = 17408 B
    const int tid = threadIdx.x;
    const int lane = tid & 63, w = tid >> 6;
    const int quad = lane >> 4, l15 = lane & 15;
    const int bs = blockIdx.x & 3;        // batch slice: batches bs*16..bs*16+15
    const int jg = blockIdx.x >> 2;       // hidden group: units jg*16..jg*16+15
    const int ks0 = 256 * w;              // this wave's K-slice

    // persistent W_hh fragments: wf[gate][kstep]; B-frag row l15 = hidden jl
    f16x8 wf[4][8];
#pragma unroll
    for (int g = 0; g < 4; ++g) {
        const f16* Wp = Whh + ((long)g * HID + jg * 16 + l15) * HID + ks0 + quad * 8;
#pragma unroll
        for (int s = 0; s < 8; ++s)
            wf[g][s] = *(const f16x8*)(Wp + s * 32);
    }
    // pin: forbid rematerialization of the weight loads inside the t-loop
#pragma unroll
    for (int g = 0; g < 4; ++g)
#pragma unroll
        for (int s = 0; s < 8; ++s)
            asm volatile("" : "+v"(wf[g][s]));

    // gate-apply assignment: thread -> (b = tid>>4, jl = tid&15)
    const int gb = tid >> 4, gj = tid & 15;
    const int bG = bs * 16 + gb, jG = jg * 16 + gj;
    unsigned* hw = (unsigned*)hseq;
    float cst = 0.f;

#pragma unroll 1
    for (int t = 0; t < SEQ; ++t) {
        // xg loads first: independent of h, latency hides under MFMA + LDS phase
        const f16* xp = xg + (((long)t * 4 + bs) * 64 + jg) * 1024 + gb * 16 + gj;
        float xgi = (float)xp[0];
        float xgf = (float)xp[256];
        float xgg = (float)xp[512];
        float xgo = (float)xp[768];

        f32x4 acc[4];
#pragma unroll
        for (int g = 0; g < 4; ++g)
#pragma unroll
            for (int r = 0; r < 4; ++r) acc[g][r] = 0.f;

        if (t > 0) {
            // h fragments: coherent (L2-bypassing) 8B atomic loads
            const unsigned long long* hp = (const unsigned long long*)
                (hseq + ((long)(t - 1) * BATCH + bs * 16 + l15) * HID + ks0 + quad * 8);
#pragma unroll
            for (int s = 0; s < 8; ++s) {
                union { unsigned long long u[2]; f16x8 v; } af;
                af.u[0] = __hip_atomic_load((unsigned long long*)(hp + s * 8),
                                            __ATOMIC_RELAXED, __HIP_MEMORY_SCOPE_AGENT);
                af.u[1] = __hip_atomic_load((unsigned long long*)(hp + s * 8 + 1),
                                            __ATOMIC_RELAXED, __HIP_MEMORY_SCOPE_AGENT);
#pragma unroll
                for (int g = 0; g < 4; ++g)
                    acc[g] = __builtin_amdgcn_mfma_f32_16x16x32_f16(af.v, wf[g][s], acc[g], 0, 0, 0);
            }
        }

        // K-reduction through LDS: C-tile value (row=quad*4+r -> batch, col=l15 -> jl)
#pragma unroll
        for (int g = 0; g < 4; ++g)
#pragma unroll
            for (int r = 0; r < 4; ++r)
                P[((w * 4 + g) * 16 + quad * 4 + r) * 17 + l15] = acc[g][r];
        __syncthreads();

        float gate[4];
#pragma unroll
        for (int g = 0; g < 4; ++g) {
            float s0 = P[((0 * 4 + g) * 16 + gb) * 17 + gj];
            float s1 = P[((1 * 4 + g) * 16 + gb) * 17 + gj];
            float s2 = P[((2 * 4 + g) * 16 + gb) * 17 + gj];
            float s3 = P[((3 * 4 + g) * 16 + gb) * 17 + gj];
            gate[g] = (s0 + s1) + (s2 + s3);
        }

        float gi = gate[0] + xgi;
        float gf = gate[1] + xgf;
        float gg = gate[2] + xgg;
        float go = gate[3] + xgo;
        float si = sigf(gi), sf = sigf(gf), so = sigf(go);
        float tg = tanh_fast(gg);
        cst = sf * cst + si * tg;
        float h = so * tanh_fast(cst);

        // publish h: pack f16 pair across adjacent lanes, write-through atomic store
        union { f16 f; unsigned short u; } cv; cv.f = (f16)h;
        unsigned hv = cv.u;
        unsigned ov = __shfl_xor(hv, 1);
        if (!(tid & 1))
            __hip_atomic_store(&hw[(((long)t * BATCH + bG) * HID + jG) >> 1],
                               hv | (ov << 16), __ATOMIC_RELAXED, __HIP_MEMORY_SCOPE_AGENT);
        if (out32) out32[((long)bG * SEQ + t) * HID + jG] = h;

        if (t + 1 < SEQ) grid_barrier_nf(bar, (unsigned)(t + 1));
    }
}

// ---------------- host ----------------------------------------------------------------
extern "C" void kernel_launch(void* const* d_in, const int* in_sizes, int n_in,
                              void* d_out, int out_size, void* d_ws, size_t ws_size,
                              hipStream_t stream) {
    (void)in_sizes; (void)n_in; (void)out_size; (void)ws_size;
    const float* x    = (const float*)d_in[0];
    const float* Wih0 = (const float*)d_in[1];
    const float* Whh0 = (const float*)d_in[2];
    const float* bih0 = (const float*)d_in[3];
    const float* bhh0 = (const float*)d_in[4];
    const float* Wih1 = (const float*)d_in[5];
    const float* Whh1 = (const float*)d_in[6];
    const float* bih1 = (const float*)d_in[7];
    const float* bhh1 = (const float*)d_in[8];

    char* ws = (char*)d_ws;
    size_t off = 0;
    auto alloc = [&](size_t bytes) { char* p = ws + off; off += (bytes + 255) & ~(size_t)255; return p; };
    f16*   XG   = (f16*)alloc((size_t)SEQ * BATCH * NG * 2);     // 256 MB
    f16*   xh   = (f16*)alloc((size_t)BATCH * SEQ * DPAD * 2);   // 56 MB
    f16*   h1   = (f16*)alloc((size_t)SEQ * BATCH * HID * 2);    // 64 MB
    f16*   W0h  = (f16*)alloc((size_t)NG * DPAD * 2);
    f16*   Wh0h = (f16*)alloc((size_t)NG * HID * 2);
    f16*   W1h  = (f16*)alloc((size_t)NG * HID * 2);
    f16*   Wh1h = (f16*)alloc((size_t)NG * HID * 2);
    float* b0   = (float*)alloc((size_t)NG * 4);
    float* b1   = (float*)alloc((size_t)NG * 4);
    unsigned* bar = (unsigned*)alloc(2048 * 4);

    prep_kernel<<<dim3(2048), dim3(256), 0, stream>>>(x, Wih0, Whh0, bih0, bhh0,
                                                      Wih1, Whh1, bih1, bhh1,
                                                      xh, W0h, Wh0h, W1h, Wh1h, b0, b1, bar);

    gemm_f16<<<dim3(8192), dim3(256), 0, stream>>>(xh, W0h, b0, XG, DPAD, 1);

    {
        const f16* xgp = XG; const f16* whp = Wh0h; f16* hp = h1;
        float* op = nullptr; unsigned* bp = bar;
        void* args[] = { (void*)&xgp, (void*)&whp, (void*)&hp, (void*)&op, (void*)&bp };
        (void)hipLaunchCooperativeKernel((const void*)lstm_layer, dim3(256), dim3(256), args, 0, stream);
    }

    gemm_f16<<<dim3(8192), dim3(256), 0, stream>>>(h1, W1h, b1, XG, HID, 2);

    {
        const f16* xgp = XG; const f16* whp = Wh1h; f16* hp = h1;
        float* op = (float*)d_out; unsigned* bp = bar + 1024;
        void* args[] = { (void*)&xgp, (void*)&whp, (void*)&hp, (void*)&op, (void*)&bp };
        (void)hipLaunchCooperativeKernel((const void*)lstm_layer, dim3(256), dim3(256), args, 0, stream);
    }
}